// Round 1
// baseline (2876.783 us; speedup 1.0000x reference)
//
#include <hip/hip_runtime.h>

// Problem constants (from reference)
constexpr int T_ = 16, F_ = 16, D_ = 512;
constexpr int N_ = 4, L_ = 4, H_ = 512, W_ = 512;
constexpr int HW_ = H_ * W_;

// One thread per (n, l, h, w). Computes the bilinear weights once, then
// loops over F=16 channels doing 4 scalar gathers from data[t, f, y, x]
// (layout (T,F,D,D), channel stride 1 MB) and one coalesced store per f.
__global__ __launch_bounds__(256) void tex_sample_kernel(
    const float* __restrict__ uv,    // (N, 2L, H, W)
    const int*   __restrict__ mask,  // (N, L, H, W)
    const float* __restrict__ data,  // (T, F, D, D)
    float*       __restrict__ out)   // (N, L*F, H, W)
{
    int idx = blockIdx.x * blockDim.x + threadIdx.x;  // over N*L*H*W
    int w = idx & (W_ - 1);
    int h = (idx >> 9) & (H_ - 1);
    int l = (idx >> 18) & (L_ - 1);
    int n = idx >> 20;

    int hw = h * W_ + w;

    float u  = uv[((size_t)(n * 2 * L_ + 2 * l)     ) * HW_ + hw];
    float v  = uv[((size_t)(n * 2 * L_ + 2 * l + 1)) * HW_ + hw];
    int  tid = mask[((size_t)(n * L_ + l)) * HW_ + hw];

    float ix = fminf(fmaxf((u + 1.0f) * (D_ * 0.5f) - 0.5f, 0.0f), (float)(D_ - 1));
    float iy = fminf(fmaxf((v + 1.0f) * (D_ * 0.5f) - 0.5f, 0.0f), (float)(D_ - 1));
    float x0f = floorf(ix), y0f = floorf(iy);
    float wx = ix - x0f, wy = iy - y0f;
    int x0 = (int)x0f, y0 = (int)y0f;
    int x1 = min(x0 + 1, D_ - 1);
    int y1 = min(y0 + 1, D_ - 1);

    float valid = (tid >= 0 && tid < T_) ? 1.0f : 0.0f;
    int t = min(max(tid, 0), T_ - 1);

    float w00 = (1.0f - wx) * (1.0f - wy) * valid;
    float w01 = wx * (1.0f - wy) * valid;
    float w10 = (1.0f - wx) * wy * valid;
    float w11 = wx * wy * valid;

    const float* dbase = data + (size_t)t * F_ * D_ * D_;
    int r0 = y0 * D_;
    int r1 = y1 * D_;
    float* obase = out + ((size_t)(n * L_ + l) * F_) * HW_ + hw;

    #pragma unroll
    for (int f = 0; f < F_; ++f) {
        const float* dp = dbase + (size_t)f * (D_ * D_);
        float v00 = dp[r0 + x0];
        float v01 = dp[r0 + x1];
        float v10 = dp[r1 + x0];
        float v11 = dp[r1 + x1];
        obase[(size_t)f * HW_] = v00 * w00 + v01 * w01 + v10 * w10 + v11 * w11;
    }
}

extern "C" void kernel_launch(void* const* d_in, const int* in_sizes, int n_in,
                              void* d_out, int out_size, void* d_ws, size_t ws_size,
                              hipStream_t stream) {
    const float* uv   = (const float*)d_in[0];
    const int*   mask = (const int*)d_in[1];
    const float* data = (const float*)d_in[2];
    float* out = (float*)d_out;

    int total = N_ * L_ * H_ * W_;  // 4,194,304 threads
    dim3 block(256);
    dim3 grid(total / 256);
    tex_sample_kernel<<<grid, block, 0, stream>>>(uv, mask, data, out);
}

// Round 2
// 791.256 us; speedup vs baseline: 3.6357x; 3.6357x over previous
//
#include <hip/hip_runtime.h>

// Problem constants (from reference)
constexpr int T_ = 16, F_ = 16, D_ = 512;
constexpr int N_ = 4, L_ = 4, H_ = 512, W_ = 512;
constexpr int HW_ = H_ * W_;
constexpr size_t DATA_ELEMS = (size_t)T_ * F_ * D_ * D_;  // 64 Mi floats = 256 MB

// ---------------------------------------------------------------------------
// Stage 1: transpose data (T,F,D,D) -> ws (T,D,D,F) so that the 16 channels
// of one texel are a single contiguous 64 B cache line.
// One thread per (t,y,x): 16 coalesced scalar loads (lane-consecutive x per
// fixed f), then one contiguous 64 B store as 4x float4.
// ---------------------------------------------------------------------------
__global__ __launch_bounds__(256) void restage_kernel(
    const float* __restrict__ data,  // (T, F, D, D)
    float*       __restrict__ ws)    // (T, D, D, F)
{
    int idx = blockIdx.x * blockDim.x + threadIdx.x;  // over T*D*D
    int x = idx & (D_ - 1);
    int y = (idx >> 9) & (D_ - 1);
    int t = idx >> 18;

    const float* p = data + (size_t)t * F_ * D_ * D_ + (size_t)y * D_ + x;
    float vals[F_];
    #pragma unroll
    for (int f = 0; f < F_; ++f) vals[f] = p[(size_t)f * (D_ * D_)];

    float4* o = (float4*)(ws + (size_t)idx * F_);
    o[0] = make_float4(vals[0],  vals[1],  vals[2],  vals[3]);
    o[1] = make_float4(vals[4],  vals[5],  vals[6],  vals[7]);
    o[2] = make_float4(vals[8],  vals[9],  vals[10], vals[11]);
    o[3] = make_float4(vals[12], vals[13], vals[14], vals[15]);
}

// ---------------------------------------------------------------------------
// Stage 2: one thread per (n,l,h,w). 4 bilinear corners, each one 64 B line
// in the restaged table, loaded as 4x float4. 16 outputs, stores coalesced
// across lanes (stride HW between channels).
// ---------------------------------------------------------------------------
__global__ __launch_bounds__(256) void tex_sample_staged_kernel(
    const float* __restrict__ uv,    // (N, 2L, H, W)
    const int*   __restrict__ mask,  // (N, L, H, W)
    const float* __restrict__ ws,    // (T, D, D, F) staged
    float*       __restrict__ out)   // (N, L*F, H, W)
{
    int idx = blockIdx.x * blockDim.x + threadIdx.x;  // over N*L*H*W
    int w = idx & (W_ - 1);
    int h = (idx >> 9) & (H_ - 1);
    int l = (idx >> 18) & (L_ - 1);
    int n = idx >> 20;
    int hw = h * W_ + w;

    float u  = uv[((size_t)(n * 2 * L_ + 2 * l)     ) * HW_ + hw];
    float v  = uv[((size_t)(n * 2 * L_ + 2 * l + 1)) * HW_ + hw];
    int  tid = mask[((size_t)(n * L_ + l)) * HW_ + hw];

    float ix = fminf(fmaxf((u + 1.0f) * (D_ * 0.5f) - 0.5f, 0.0f), (float)(D_ - 1));
    float iy = fminf(fmaxf((v + 1.0f) * (D_ * 0.5f) - 0.5f, 0.0f), (float)(D_ - 1));
    float x0f = floorf(ix), y0f = floorf(iy);
    float wx = ix - x0f, wy = iy - y0f;
    int x0 = (int)x0f, y0 = (int)y0f;
    int x1 = min(x0 + 1, D_ - 1);
    int y1 = min(y0 + 1, D_ - 1);

    float valid = (tid >= 0 && tid < T_) ? 1.0f : 0.0f;
    int t = min(max(tid, 0), T_ - 1);

    float w00 = (1.0f - wx) * (1.0f - wy) * valid;
    float w01 = wx * (1.0f - wy) * valid;
    float w10 = (1.0f - wx) * wy * valid;
    float w11 = wx * wy * valid;

    size_t tbase = (size_t)t * D_ * D_;
    const float4* p00 = (const float4*)(ws + (tbase + (size_t)y0 * D_ + x0) * F_);
    const float4* p01 = (const float4*)(ws + (tbase + (size_t)y0 * D_ + x1) * F_);
    const float4* p10 = (const float4*)(ws + (tbase + (size_t)y1 * D_ + x0) * F_);
    const float4* p11 = (const float4*)(ws + (tbase + (size_t)y1 * D_ + x1) * F_);

    float acc[F_];
    #pragma unroll
    for (int j = 0; j < 4; ++j) {
        float4 a = p00[j];
        acc[4*j+0] = a.x * w00; acc[4*j+1] = a.y * w00;
        acc[4*j+2] = a.z * w00; acc[4*j+3] = a.w * w00;
    }
    #pragma unroll
    for (int j = 0; j < 4; ++j) {
        float4 a = p01[j];
        acc[4*j+0] += a.x * w01; acc[4*j+1] += a.y * w01;
        acc[4*j+2] += a.z * w01; acc[4*j+3] += a.w * w01;
    }
    #pragma unroll
    for (int j = 0; j < 4; ++j) {
        float4 a = p10[j];
        acc[4*j+0] += a.x * w10; acc[4*j+1] += a.y * w10;
        acc[4*j+2] += a.z * w10; acc[4*j+3] += a.w * w10;
    }
    #pragma unroll
    for (int j = 0; j < 4; ++j) {
        float4 a = p11[j];
        acc[4*j+0] += a.x * w11; acc[4*j+1] += a.y * w11;
        acc[4*j+2] += a.z * w11; acc[4*j+3] += a.w * w11;
    }

    float* obase = out + ((size_t)(n * L_ + l) * F_) * HW_ + hw;
    #pragma unroll
    for (int f = 0; f < F_; ++f) obase[(size_t)f * HW_] = acc[f];
}

// ---------------------------------------------------------------------------
// Fallback (R0 baseline) if the workspace is too small for the staged table.
// ---------------------------------------------------------------------------
__global__ __launch_bounds__(256) void tex_sample_kernel(
    const float* __restrict__ uv,
    const int*   __restrict__ mask,
    const float* __restrict__ data,
    float*       __restrict__ out)
{
    int idx = blockIdx.x * blockDim.x + threadIdx.x;
    int w = idx & (W_ - 1);
    int h = (idx >> 9) & (H_ - 1);
    int l = (idx >> 18) & (L_ - 1);
    int n = idx >> 20;
    int hw = h * W_ + w;

    float u  = uv[((size_t)(n * 2 * L_ + 2 * l)     ) * HW_ + hw];
    float v  = uv[((size_t)(n * 2 * L_ + 2 * l + 1)) * HW_ + hw];
    int  tid = mask[((size_t)(n * L_ + l)) * HW_ + hw];

    float ix = fminf(fmaxf((u + 1.0f) * (D_ * 0.5f) - 0.5f, 0.0f), (float)(D_ - 1));
    float iy = fminf(fmaxf((v + 1.0f) * (D_ * 0.5f) - 0.5f, 0.0f), (float)(D_ - 1));
    float x0f = floorf(ix), y0f = floorf(iy);
    float wx = ix - x0f, wy = iy - y0f;
    int x0 = (int)x0f, y0 = (int)y0f;
    int x1 = min(x0 + 1, D_ - 1);
    int y1 = min(y0 + 1, D_ - 1);

    float valid = (tid >= 0 && tid < T_) ? 1.0f : 0.0f;
    int t = min(max(tid, 0), T_ - 1);

    float w00 = (1.0f - wx) * (1.0f - wy) * valid;
    float w01 = wx * (1.0f - wy) * valid;
    float w10 = (1.0f - wx) * wy * valid;
    float w11 = wx * wy * valid;

    const float* dbase = data + (size_t)t * F_ * D_ * D_;
    int r0 = y0 * D_;
    int r1 = y1 * D_;
    float* obase = out + ((size_t)(n * L_ + l) * F_) * HW_ + hw;

    #pragma unroll
    for (int f = 0; f < F_; ++f) {
        const float* dp = dbase + (size_t)f * (D_ * D_);
        float v00 = dp[r0 + x0];
        float v01 = dp[r0 + x1];
        float v10 = dp[r1 + x0];
        float v11 = dp[r1 + x1];
        obase[(size_t)f * HW_] = v00 * w00 + v01 * w01 + v10 * w10 + v11 * w11;
    }
}

extern "C" void kernel_launch(void* const* d_in, const int* in_sizes, int n_in,
                              void* d_out, int out_size, void* d_ws, size_t ws_size,
                              hipStream_t stream) {
    const float* uv   = (const float*)d_in[0];
    const int*   mask = (const int*)d_in[1];
    const float* data = (const float*)d_in[2];
    float* out = (float*)d_out;

    int total = N_ * L_ * H_ * W_;  // 4,194,304 threads

    if (ws_size >= DATA_ELEMS * sizeof(float)) {
        float* staged = (float*)d_ws;
        int stage_total = T_ * D_ * D_;  // 4,194,304
        restage_kernel<<<stage_total / 256, 256, 0, stream>>>(data, staged);
        tex_sample_staged_kernel<<<total / 256, 256, 0, stream>>>(uv, mask, staged, out);
    } else {
        tex_sample_kernel<<<total / 256, 256, 0, stream>>>(uv, mask, data, out);
    }
}